// Round 2
// baseline (286.735 us; speedup 1.0000x reference)
//
#include <hip/hip_runtime.h>
#include <math.h>

#define NTOT 16384
#define NSEG 2048
#define TROW 65
#define TSTRIDE 133120ull   // 2048*65 floats per task (local tables)
#define CSTRIDE 8385ull     // 129*65 floats per task (scanned chunk tables)

// ws float offsets
#define OFF_HH   0ull         // 16384*256 (hc reuses this region)
#define OFF_XC   4194304ull   // 16384*256 (TA/TS time-share this region)
#define OFF_S1H  8388608ull   // 65536
#define OFF_S2H  8454144ull   // 65536
#define OFF_S1O  8519680ull   // 16384
#define OFF_S2O  8536064ull   // 16384
#define OFF_SVAL 8552448ull   // 32*2048
#define OFF_WN   8617984ull   // 32*2048
#define OFF_SIDX 8683520ull   // 32*2048 ints
#define OFF_CA   8749056ull   // 32*129*65
#define OFF_CS   9017376ull   // 32*129*65
#define OFF_A    9285696ull   // 32*2048*65
#define OFF_S    13545536ull  // 32*2048*65 -> end 17805376 floats
#define OFF_CNT  17805376ull  // 32 ints (task completion counters)
// TA/TS (chunk totals, 32*128*65 each) live inside the xc region:
//   TA = OFF_XC, TS = OFF_XC + 266240. Dead before query_k<0> writes xc.

__device__ inline unsigned long long pack_key(float v, int idx) {
    unsigned u = __float_as_uint(v);
    u = (u & 0x80000000u) ? ~u : (u | 0x80000000u);
    return ((unsigned long long)u << 32) | (unsigned)idx;
}
__device__ inline float unpack_key(unsigned long long k) {
    unsigned u = (unsigned)(k >> 32);
    u = (u & 0x80000000u) ? (u ^ 0x80000000u) : ~u;
    return __uint_as_float(u);
}
__device__ inline unsigned long long shfl_xor_u64(unsigned long long x, int mask) {
    unsigned lo = (unsigned)x, hi = (unsigned)(x >> 32);
    lo = (unsigned)__shfl_xor((int)lo, mask, 64);
    hi = (unsigned)__shfl_xor((int)hi, mask, 64);
    return ((unsigned long long)hi << 32) | lo;
}

// ---------------- GEMM 1 + fused s1/s2 projection ----------------
__global__ __launch_bounds__(256) void gemm1_k(const float* __restrict__ X,
                                               const float* __restrict__ Wh,
                                               const float* __restrict__ aH,
                                               float* __restrict__ hh,
                                               float* __restrict__ s1h,
                                               float* __restrict__ s2h) {
    __shared__ float As[64][68];
    __shared__ float Bs[64][68];
    const int tid = threadIdx.x;
    const int bm = blockIdx.x, h = blockIdx.y;
    const int c0 = tid & 63, r0 = tid >> 6;
#pragma unroll
    for (int r = 0; r < 16; ++r) {
        int row = r0 + r * 4;
        As[c0][row] = X[(size_t)(bm * 64 + row) * 64 + c0];
        Bs[row][c0] = Wh[h * 4096 + row * 64 + c0];
    }
    __syncthreads();
    const int tx = tid & 15, ty = tid >> 4;
    const int m0 = ty * 4, n0 = tx * 4;
    float acc[4][4] = {};
#pragma unroll
    for (int kk = 0; kk < 64; ++kk) {
        float4 a = *(const float4*)&As[kk][m0];
        float4 b = *(const float4*)&Bs[kk][n0];
        acc[0][0] += a.x * b.x; acc[0][1] += a.x * b.y; acc[0][2] += a.x * b.z; acc[0][3] += a.x * b.w;
        acc[1][0] += a.y * b.x; acc[1][1] += a.y * b.y; acc[1][2] += a.y * b.z; acc[1][3] += a.y * b.w;
        acc[2][0] += a.z * b.x; acc[2][1] += a.z * b.y; acc[2][2] += a.z * b.z; acc[2][3] += a.z * b.w;
        acc[3][0] += a.w * b.x; acc[3][1] += a.w * b.y; acc[3][2] += a.w * b.z; acc[3][3] += a.w * b.w;
    }
#pragma unroll
    for (int i = 0; i < 4; ++i) {
        float4 v = make_float4(acc[i][0], acc[i][1], acc[i][2], acc[i][3]);
        *(float4*)&hh[(size_t)(bm * 64 + m0 + i) * 256 + h * 64 + n0] = v;
    }
#pragma unroll
    for (int i = 0; i < 4; ++i) {
        float p1 = 0.f, p2 = 0.f;
#pragma unroll
        for (int jj = 0; jj < 4; ++jj) {
            p1 += acc[i][jj] * aH[h * 128 + n0 + jj];
            p2 += acc[i][jj] * aH[h * 128 + 64 + n0 + jj];
        }
#pragma unroll
        for (int off = 8; off; off >>= 1) {
            p1 += __shfl_xor(p1, off, 16);
            p2 += __shfl_xor(p2, off, 16);
        }
        if (tx == 0) {
            s1h[h * NTOT + bm * 64 + m0 + i] = p1;
            s2h[h * NTOT + bm * 64 + m0 + i] = p2;
        }
    }
}

// ---------------- GEMM 2 (BM=32 tiles, 512 blocks) + fused s1/s2 projection ----------------
__global__ __launch_bounds__(256) void gemm2_k(const float* __restrict__ XC,
                                               const float* __restrict__ Wo,
                                               const float* __restrict__ aO,
                                               float* __restrict__ hc,
                                               float* __restrict__ s1o,
                                               float* __restrict__ s2o) {
    __shared__ float As[64][34];   // [k][m], BM=32 (+2 pad)
    __shared__ float Bs[64][68];   // [k][n]
    const int tid = threadIdx.x;
    const int bm = blockIdx.x;
    const int c0 = tid & 63, r0 = tid >> 6;
    const int tx = tid & 15, ty = tid >> 4;
    const int m0 = ty * 2, n0 = tx * 4;
    float acc[2][4] = {};
    for (int kt = 0; kt < 4; ++kt) {
#pragma unroll
        for (int r = 0; r < 8; ++r) {
            int row = r0 + r * 4;
            As[c0][row] = XC[(size_t)(bm * 32 + row) * 256 + kt * 64 + c0];
        }
#pragma unroll
        for (int r = 0; r < 16; ++r) {
            int row = r0 + r * 4;
            Bs[row][c0] = Wo[(kt * 64 + row) * 64 + c0];
        }
        __syncthreads();
#pragma unroll
        for (int kk = 0; kk < 64; ++kk) {
            float2 a = *(const float2*)&As[kk][m0];
            float4 b = *(const float4*)&Bs[kk][n0];
            acc[0][0] += a.x * b.x; acc[0][1] += a.x * b.y; acc[0][2] += a.x * b.z; acc[0][3] += a.x * b.w;
            acc[1][0] += a.y * b.x; acc[1][1] += a.y * b.y; acc[1][2] += a.y * b.z; acc[1][3] += a.y * b.w;
        }
        __syncthreads();
    }
#pragma unroll
    for (int i = 0; i < 2; ++i) {
        float4 v = make_float4(acc[i][0], acc[i][1], acc[i][2], acc[i][3]);
        *(float4*)&hc[(size_t)(bm * 32 + m0 + i) * 64 + n0] = v;
    }
#pragma unroll
    for (int i = 0; i < 2; ++i) {
        float p1 = 0.f, p2 = 0.f;
#pragma unroll
        for (int jj = 0; jj < 4; ++jj) {
            p1 += acc[i][jj] * aO[n0 + jj];
            p2 += acc[i][jj] * aO[64 + n0 + jj];
        }
#pragma unroll
        for (int off = 8; off; off >>= 1) {
            p1 += __shfl_xor(p1, off, 16);
            p2 += __shfl_xor(p2, off, 16);
        }
        if (tx == 0) {
            s1o[bm * 32 + m0 + i] = p1;
            s2o[bm * 32 + m0 + i] = p2;
        }
    }
}

// ---------------- lean bitonic sort: 1 block per task, double-buffered LDS exchanges ----------------
__global__ __launch_bounds__(1024) void sort_k(const float* __restrict__ s2_all,
                                               int heads,
                                               float* __restrict__ g_sval,
                                               int* __restrict__ g_sidx,
                                               float* __restrict__ g_wN) {
    __shared__ unsigned long long sA[2][1024];
    __shared__ unsigned long long sB[2][1024];
    __shared__ float sM2;
    const int tid = threadIdx.x, t = blockIdx.x;
    const int g = t / heads, h = t % heads;
    const float* s2p = s2_all + (size_t)h * NTOT + (size_t)g * NSEG;

    unsigned long long a0 = pack_key(s2p[tid], tid);
    unsigned long long a1 = pack_key(s2p[tid + 1024], tid + 1024);
    int p = 0;
    for (int k = 2; k <= 2048; k <<= 1) {
        const bool up0 = (tid & k) == 0;
        const bool up1 = (((tid + 1024) & k) == 0);
        for (int j = k >> 1; j > 0; j >>= 1) {
            if (j >= 1024) {
                unsigned long long lo = a0 < a1 ? a0 : a1;
                unsigned long long hi = a0 < a1 ? a1 : a0;
                a0 = up0 ? lo : hi;
                a1 = up0 ? hi : lo;
            } else if (j >= 64) {
                sA[p][tid] = a0; sB[p][tid] = a1;
                __syncthreads();
                unsigned long long q0 = sA[p][tid ^ j], q1 = sB[p][tid ^ j];
                bool lower = (tid & j) == 0;
                a0 = ((a0 < q0) == (lower == up0)) ? a0 : q0;
                a1 = ((a1 < q1) == (lower == up1)) ? a1 : q1;
                p ^= 1;
            } else {
                unsigned long long q0 = shfl_xor_u64(a0, j);
                unsigned long long q1 = shfl_xor_u64(a1, j);
                bool lower = (tid & j) == 0;
                a0 = ((a0 < q0) == (lower == up0)) ? a0 : q0;
                a1 = ((a1 < q1) == (lower == up1)) ? a1 : q1;
            }
        }
    }
    float v0 = unpack_key(a0), v1 = unpack_key(a1);
    if (tid == 1023) sM2 = v1;
    __syncthreads();
    const float M2 = sM2;
    int i0 = (int)(unsigned)(a0 & 0xffffffffu);
    int i1 = (int)(unsigned)(a1 & 0xffffffffu);
    float w0 = __expf(0.2f * (v0 - M2));
    float w1 = __expf(0.2f * (v1 - M2));
    size_t o = (size_t)t * NSEG;
    g_sval[o + tid] = v0; g_sval[o + tid + 1024] = v1;
    g_sidx[o + tid] = i0; g_sidx[o + tid + 1024] = i1;
    g_wN[o + tid] = w0;   g_wN[o + tid + 1024] = w1;
}

// ---------------- wide table build + fused last-block chunk scan ----------------
__global__ __launch_bounds__(256) void tabw_k(const float* __restrict__ V,
                                              int heads, int vstride, int lastv,
                                              const int* __restrict__ g_sidx,
                                              const float* __restrict__ g_wN,
                                              float* __restrict__ g_A, float* __restrict__ g_S,
                                              float* __restrict__ g_TA, float* __restrict__ g_TS,
                                              float* __restrict__ g_CA, float* __restrict__ g_CS,
                                              int* __restrict__ g_cnt) {
    __shared__ int s_last;
    const int t = blockIdx.y, g = t / heads, h = t % heads;
    const int wv = threadIdx.x >> 6, lane = threadIdx.x & 63;
    const int c = blockIdx.x * 4 + wv;
    const int base = c * 16;
    const float* Vp = V + (size_t)g * NSEG * vstride + h * 64;
    const int* sidx = g_sidx + (size_t)t * NSEG + base;
    const float* wnp = g_wN + (size_t)t * NSEG + base;
    float wn[16], vv[16];
#pragma unroll
    for (int j = 0; j < 16; ++j) wn[j] = wnp[j];
#pragma unroll
    for (int j = 0; j < 16; ++j) vv[j] = Vp[(size_t)sidx[j] * vstride + lane];
    float* A = g_A + (size_t)t * TSTRIDE;
    float* S = g_S + (size_t)t * TSTRIDE;
    // exclusive within-chunk prefix (A side, leaky 0.2 weights) — nt stores (single-use, 34MB)
    float accA = 0.f, scaA = 0.f;
#pragma unroll
    for (int j = 0; j < 16; ++j) {
        size_t pos = base + j;
        __builtin_nontemporal_store(accA, &A[pos * TROW + lane]);
        if (lane == 0) __builtin_nontemporal_store(scaA, &A[pos * TROW + 64]);
        accA += wn[j] * vv[j]; scaA += wn[j];
    }
    g_TA[((size_t)t * 128 + c) * TROW + lane] = accA;
    if (lane == 0) g_TA[((size_t)t * 128 + c) * TROW + 64] = scaA;
    // inclusive within-chunk suffix (S side, full-strength weights)
    float accS = 0.f, scaS = 0.f;
#pragma unroll
    for (int j = 15; j >= 0; --j) {
        float w = wn[j], w2 = w * w, wp = w2 * w2 * w;
        accS += wp * vv[j]; scaS += wp;
        size_t pos = base + j;
        __builtin_nontemporal_store(accS, &S[pos * TROW + lane]);
        if (lane == 0) __builtin_nontemporal_store(scaS, &S[pos * TROW + 64]);
    }
    g_TS[((size_t)t * 128 + c) * TROW + lane] = accS;
    if (lane == 0) g_TS[((size_t)t * 128 + c) * TROW + 64] = scaS;

    // ---- last-block-done: scan chunk totals for this task (replaces scan_k) ----
    if (threadIdx.x == 0) {
        __threadfence();
        int old = atomicAdd(&g_cnt[t], 1);
        s_last = (old == lastv) ? 1 : 0;
    }
    __syncthreads();
    if (!s_last) return;
    __threadfence();  // acquire: other blocks' TA/TS visible
    const int tid = threadIdx.x;
    if (tid < 65) {
        const float* TA = g_TA + (size_t)t * 128 * TROW + tid;
        float* CA = g_CA + (size_t)t * CSTRIDE + tid;
        float run = 0.f;
#pragma unroll 4
        for (int cc = 0; cc < 128; ++cc) { CA[cc * TROW] = run; run += TA[cc * TROW]; }
        CA[128 * TROW] = run;   // row 128 = full total (used by k==2048 queries)
    } else if (tid >= 128 && tid < 193) {
        const int d = tid - 128;
        const float* TS = g_TS + (size_t)t * 128 * TROW + d;
        float* CS = g_CS + (size_t)t * CSTRIDE + d;
        float run = 0.f;
#pragma unroll 4
        for (int cc = 127; cc >= 0; --cc) { CS[cc * TROW] = run; run += TS[cc * TROW]; }
    }
}

// ---------------- query: binary search + 2 local rows + 2 chunk-offset rows; 16 queries per wave ----------------
template <int MODE>  // 0: ELU -> xc ; 1: ELU + log_softmax -> out
__global__ __launch_bounds__(256) void query_k(const float* __restrict__ s1_all,
                                               float* __restrict__ out,
                                               int heads, int ostride,
                                               const float* __restrict__ g_sval,
                                               const float* __restrict__ g_A,
                                               const float* __restrict__ g_S,
                                               const float* __restrict__ g_CA,
                                               const float* __restrict__ g_CS) {
    __shared__ float sval[NSEG];
    const int tid = threadIdx.x;
    const int t = blockIdx.y, g = t / heads, h = t % heads;
    const float4* sv4 = (const float4*)(g_sval + (size_t)t * NSEG);
    for (int i = tid; i < NSEG / 4; i += 256) ((float4*)sval)[i] = sv4[i];
    __syncthreads();
    const float M2 = sval[NSEG - 1];
    const int lane = tid & 63, wv = tid >> 6;
    const int q0 = blockIdx.x * 64 + wv * 16;
    const float* s1p = s1_all + (size_t)h * NTOT + (size_t)g * NSEG;
    float* outp = out + (size_t)g * NSEG * ostride + h * 64;
    const float* A = g_A + (size_t)t * TSTRIDE;
    const float* S = g_S + (size_t)t * TSTRIDE;
    const float* CA = g_CA + (size_t)t * CSTRIDE;
    const float* CS = g_CS + (size_t)t * CSTRIDE;
    int myq = q0 + (lane & 15);
    float s1v = s1p[myq];
    float th = -s1v;
    int lo = 0, hi = NSEG;
    while (lo < hi) { int mid = (lo + hi) >> 1; if (sval[mid] <= th) lo = mid + 1; else hi = mid; }
#pragma unroll
    for (int j = 0; j < 16; ++j) {
        int k = __shfl(lo, j, 64);
        float s1q = __shfl(s1v, j, 64);
        float accA, scaA, accS, scaS;
        if (k < NSEG) {
            const int c = k >> 4;
            const float* rowA = A + (size_t)k * TROW;
            const float* rowS = S + (size_t)k * TROW;
            const float* rowCA = CA + (size_t)c * TROW;
            const float* rowCS = CS + (size_t)c * TROW;
            accA = __builtin_nontemporal_load(&rowA[lane]) + rowCA[lane];
            scaA = __builtin_nontemporal_load(&rowA[64]) + rowCA[64];
            accS = __builtin_nontemporal_load(&rowS[lane]) + rowCS[lane];
            scaS = __builtin_nontemporal_load(&rowS[64]) + rowCS[64];
        } else {
            accA = CA[128 * TROW + lane]; scaA = CA[128 * TROW + 64];
            accS = 0.f; scaS = 0.f;
        }
        float cc = __expf(-0.8f * fmaxf(s1q + M2, 0.f));
        float o = (accS + cc * accA) / (scaS + cc * scaA);
        o = o > 0.f ? o : expm1f(o);  // ELU
        int q = q0 + j;
        if (MODE == 0) {
            outp[(size_t)q * ostride + lane] = o;
        } else {
            float m = o;
#pragma unroll
            for (int off = 32; off; off >>= 1) m = fmaxf(m, __shfl_xor(m, off, 64));
            float e = __expf(o - m);
#pragma unroll
            for (int off = 32; off; off >>= 1) e += __shfl_xor(e, off, 64);
            outp[(size_t)q * ostride + lane] = o - m - __logf(e);
        }
    }
}

extern "C" void kernel_launch(void* const* d_in, const int* in_sizes, int n_in,
                              void* d_out, int out_size, void* d_ws, size_t ws_size,
                              hipStream_t stream) {
    const float* h_states = (const float*)d_in[0];
    const float* W_heads = (const float*)d_in[1];
    const float* a_heads = (const float*)d_in[2];
    const float* W_out = (const float*)d_in[3];
    const float* a_out = (const float*)d_in[4];
    float* w = (float*)d_ws;
    float* hh = w + OFF_HH;
    float* xc = w + OFF_XC;
    float* hc = w + OFF_HH;  // reuse: hh dead after tabw (head layer)
    float* s1h = w + OFF_S1H;
    float* s2h = w + OFF_S2H;
    float* s1o = w + OFF_S1O;
    float* s2o = w + OFF_S2O;
    float* g_sval = w + OFF_SVAL;
    float* g_wN = w + OFF_WN;
    int* g_sidx = (int*)(w + OFF_SIDX);
    float* g_TA = w + OFF_XC;            // time-shared with xc (dead before query writes xc)
    float* g_TS = w + OFF_XC + 266240;   // "
    float* g_CA = w + OFF_CA;
    float* g_CS = w + OFF_CS;
    float* g_A = w + OFF_A;
    float* g_S = w + OFF_S;
    int* g_cnt = (int*)(w + OFF_CNT);
    float* outp = (float*)d_out;

    hipMemsetAsync(g_cnt, 0, 32 * sizeof(int), stream);
    gemm1_k<<<dim3(256, 4), 256, 0, stream>>>(h_states, W_heads, a_heads, hh, s1h, s2h);
    sort_k<<<32, 1024, 0, stream>>>(s2h, 4, g_sval, g_sidx, g_wN);
    tabw_k<<<dim3(32, 32), 256, 0, stream>>>(hh, 4, 256, 31, g_sidx, g_wN, g_A, g_S, g_TA, g_TS, g_CA, g_CS, g_cnt);
    query_k<0><<<dim3(32, 32), 256, 0, stream>>>(s1h, xc, 4, 256, g_sval, g_A, g_S, g_CA, g_CS);
    gemm2_k<<<512, 256, 0, stream>>>(xc, W_out, a_out, hc, s1o, s2o);
    sort_k<<<8, 1024, 0, stream>>>(s2o, 1, g_sval, g_sidx, g_wN);
    tabw_k<<<dim3(32, 8), 256, 0, stream>>>(hc, 1, 64, 63, g_sidx, g_wN, g_A, g_S, g_TA, g_TS, g_CA, g_CS, g_cnt);
    query_k<1><<<dim3(32, 8), 256, 0, stream>>>(s1o, outp, 1, 64, g_sval, g_A, g_S, g_CA, g_CS);
}

// Round 3
// 202.024 us; speedup vs baseline: 1.4193x; 1.4193x over previous
//
#include <hip/hip_runtime.h>
#include <math.h>

#define NTOT 16384
#define NSEG 2048
#define TROW 65
#define TSTRIDE 133120ull   // 2048*65 floats per task (local tables)
#define CSTRIDE 8385ull     // 129*65 floats per task (scanned chunk tables)

// ws float offsets
#define OFF_HH   0ull         // 16384*256 (hc reuses this region)
#define OFF_XC   4194304ull   // 16384*256 (TA/TS time-share this region)
#define OFF_S1H  8388608ull   // 65536
#define OFF_S2H  8454144ull   // 65536
#define OFF_S1O  8519680ull   // 16384
#define OFF_S2O  8536064ull   // 16384
#define OFF_SVAL 8552448ull   // 32*2048
#define OFF_WN   8617984ull   // 32*2048
#define OFF_SIDX 8683520ull   // 32*2048 ints
#define OFF_CA   8749056ull   // 32*129*65
#define OFF_CS   9017376ull   // 32*129*65
#define OFF_A    9285696ull   // 32*2048*65
#define OFF_S    13545536ull  // 32*2048*65 -> end 17805376 floats
// TA/TS (chunk totals, 32*128*65 each) live inside the xc region:
//   TA = OFF_XC, TS = OFF_XC + 266240. Dead before query_k<0> writes xc.

__device__ inline unsigned long long pack_key(float v, int idx) {
    unsigned u = __float_as_uint(v);
    u = (u & 0x80000000u) ? ~u : (u | 0x80000000u);
    return ((unsigned long long)u << 32) | (unsigned)idx;
}
__device__ inline float unpack_key(unsigned long long k) {
    unsigned u = (unsigned)(k >> 32);
    u = (u & 0x80000000u) ? (u ^ 0x80000000u) : ~u;
    return __uint_as_float(u);
}
__device__ inline unsigned long long shfl_xor_u64(unsigned long long x, int mask) {
    unsigned lo = (unsigned)x, hi = (unsigned)(x >> 32);
    lo = (unsigned)__shfl_xor((int)lo, mask, 64);
    hi = (unsigned)__shfl_xor((int)hi, mask, 64);
    return ((unsigned long long)hi << 32) | lo;
}

// ---------------- GEMM 1 + fused s1/s2 projection ----------------
__global__ __launch_bounds__(256) void gemm1_k(const float* __restrict__ X,
                                               const float* __restrict__ Wh,
                                               const float* __restrict__ aH,
                                               float* __restrict__ hh,
                                               float* __restrict__ s1h,
                                               float* __restrict__ s2h) {
    __shared__ float As[64][68];
    __shared__ float Bs[64][68];
    const int tid = threadIdx.x;
    const int bm = blockIdx.x, h = blockIdx.y;
    const int c0 = tid & 63, r0 = tid >> 6;
#pragma unroll
    for (int r = 0; r < 16; ++r) {
        int row = r0 + r * 4;
        As[c0][row] = X[(size_t)(bm * 64 + row) * 64 + c0];
        Bs[row][c0] = Wh[h * 4096 + row * 64 + c0];
    }
    __syncthreads();
    const int tx = tid & 15, ty = tid >> 4;
    const int m0 = ty * 4, n0 = tx * 4;
    float acc[4][4] = {};
#pragma unroll
    for (int kk = 0; kk < 64; ++kk) {
        float4 a = *(const float4*)&As[kk][m0];
        float4 b = *(const float4*)&Bs[kk][n0];
        acc[0][0] += a.x * b.x; acc[0][1] += a.x * b.y; acc[0][2] += a.x * b.z; acc[0][3] += a.x * b.w;
        acc[1][0] += a.y * b.x; acc[1][1] += a.y * b.y; acc[1][2] += a.y * b.z; acc[1][3] += a.y * b.w;
        acc[2][0] += a.z * b.x; acc[2][1] += a.z * b.y; acc[2][2] += a.z * b.z; acc[2][3] += a.z * b.w;
        acc[3][0] += a.w * b.x; acc[3][1] += a.w * b.y; acc[3][2] += a.w * b.z; acc[3][3] += a.w * b.w;
    }
#pragma unroll
    for (int i = 0; i < 4; ++i) {
        float4 v = make_float4(acc[i][0], acc[i][1], acc[i][2], acc[i][3]);
        *(float4*)&hh[(size_t)(bm * 64 + m0 + i) * 256 + h * 64 + n0] = v;
    }
#pragma unroll
    for (int i = 0; i < 4; ++i) {
        float p1 = 0.f, p2 = 0.f;
#pragma unroll
        for (int jj = 0; jj < 4; ++jj) {
            p1 += acc[i][jj] * aH[h * 128 + n0 + jj];
            p2 += acc[i][jj] * aH[h * 128 + 64 + n0 + jj];
        }
#pragma unroll
        for (int off = 8; off; off >>= 1) {
            p1 += __shfl_xor(p1, off, 16);
            p2 += __shfl_xor(p2, off, 16);
        }
        if (tx == 0) {
            s1h[h * NTOT + bm * 64 + m0 + i] = p1;
            s2h[h * NTOT + bm * 64 + m0 + i] = p2;
        }
    }
}

// ---------------- GEMM 2 (BM=32 tiles, 512 blocks) + fused s1/s2 projection ----------------
__global__ __launch_bounds__(256) void gemm2_k(const float* __restrict__ XC,
                                               const float* __restrict__ Wo,
                                               const float* __restrict__ aO,
                                               float* __restrict__ hc,
                                               float* __restrict__ s1o,
                                               float* __restrict__ s2o) {
    __shared__ float As[64][34];   // [k][m], BM=32 (+2 pad)
    __shared__ float Bs[64][68];   // [k][n]
    const int tid = threadIdx.x;
    const int bm = blockIdx.x;
    const int c0 = tid & 63, r0 = tid >> 6;
    const int tx = tid & 15, ty = tid >> 4;
    const int m0 = ty * 2, n0 = tx * 4;
    float acc[2][4] = {};
    for (int kt = 0; kt < 4; ++kt) {
#pragma unroll
        for (int r = 0; r < 8; ++r) {
            int row = r0 + r * 4;
            As[c0][row] = XC[(size_t)(bm * 32 + row) * 256 + kt * 64 + c0];
        }
#pragma unroll
        for (int r = 0; r < 16; ++r) {
            int row = r0 + r * 4;
            Bs[row][c0] = Wo[(kt * 64 + row) * 64 + c0];
        }
        __syncthreads();
#pragma unroll
        for (int kk = 0; kk < 64; ++kk) {
            float2 a = *(const float2*)&As[kk][m0];
            float4 b = *(const float4*)&Bs[kk][n0];
            acc[0][0] += a.x * b.x; acc[0][1] += a.x * b.y; acc[0][2] += a.x * b.z; acc[0][3] += a.x * b.w;
            acc[1][0] += a.y * b.x; acc[1][1] += a.y * b.y; acc[1][2] += a.y * b.z; acc[1][3] += a.y * b.w;
        }
        __syncthreads();
    }
#pragma unroll
    for (int i = 0; i < 2; ++i) {
        float4 v = make_float4(acc[i][0], acc[i][1], acc[i][2], acc[i][3]);
        *(float4*)&hc[(size_t)(bm * 32 + m0 + i) * 64 + n0] = v;
    }
#pragma unroll
    for (int i = 0; i < 2; ++i) {
        float p1 = 0.f, p2 = 0.f;
#pragma unroll
        for (int jj = 0; jj < 4; ++jj) {
            p1 += acc[i][jj] * aO[n0 + jj];
            p2 += acc[i][jj] * aO[64 + n0 + jj];
        }
#pragma unroll
        for (int off = 8; off; off >>= 1) {
            p1 += __shfl_xor(p1, off, 16);
            p2 += __shfl_xor(p2, off, 16);
        }
        if (tx == 0) {
            s1o[bm * 32 + m0 + i] = p1;
            s2o[bm * 32 + m0 + i] = p2;
        }
    }
}

// ---------------- lean bitonic sort: 1 block per task, double-buffered LDS exchanges ----------------
__global__ __launch_bounds__(1024) void sort_k(const float* __restrict__ s2_all,
                                               int heads,
                                               float* __restrict__ g_sval,
                                               int* __restrict__ g_sidx,
                                               float* __restrict__ g_wN) {
    __shared__ unsigned long long sA[2][1024];
    __shared__ unsigned long long sB[2][1024];
    __shared__ float sM2;
    const int tid = threadIdx.x, t = blockIdx.x;
    const int g = t / heads, h = t % heads;
    const float* s2p = s2_all + (size_t)h * NTOT + (size_t)g * NSEG;

    unsigned long long a0 = pack_key(s2p[tid], tid);
    unsigned long long a1 = pack_key(s2p[tid + 1024], tid + 1024);
    int p = 0;
    for (int k = 2; k <= 2048; k <<= 1) {
        const bool up0 = (tid & k) == 0;
        const bool up1 = (((tid + 1024) & k) == 0);
        for (int j = k >> 1; j > 0; j >>= 1) {
            if (j >= 1024) {
                unsigned long long lo = a0 < a1 ? a0 : a1;
                unsigned long long hi = a0 < a1 ? a1 : a0;
                a0 = up0 ? lo : hi;
                a1 = up0 ? hi : lo;
            } else if (j >= 64) {
                sA[p][tid] = a0; sB[p][tid] = a1;
                __syncthreads();
                unsigned long long q0 = sA[p][tid ^ j], q1 = sB[p][tid ^ j];
                bool lower = (tid & j) == 0;
                a0 = ((a0 < q0) == (lower == up0)) ? a0 : q0;
                a1 = ((a1 < q1) == (lower == up1)) ? a1 : q1;
                p ^= 1;
            } else {
                unsigned long long q0 = shfl_xor_u64(a0, j);
                unsigned long long q1 = shfl_xor_u64(a1, j);
                bool lower = (tid & j) == 0;
                a0 = ((a0 < q0) == (lower == up0)) ? a0 : q0;
                a1 = ((a1 < q1) == (lower == up1)) ? a1 : q1;
            }
        }
    }
    float v0 = unpack_key(a0), v1 = unpack_key(a1);
    if (tid == 1023) sM2 = v1;
    __syncthreads();
    const float M2 = sM2;
    int i0 = (int)(unsigned)(a0 & 0xffffffffu);
    int i1 = (int)(unsigned)(a1 & 0xffffffffu);
    float w0 = __expf(0.2f * (v0 - M2));
    float w1 = __expf(0.2f * (v1 - M2));
    size_t o = (size_t)t * NSEG;
    g_sval[o + tid] = v0; g_sval[o + tid + 1024] = v1;
    g_sidx[o + tid] = i0; g_sidx[o + tid + 1024] = i1;
    g_wN[o + tid] = w0;   g_wN[o + tid + 1024] = w1;
}

// ---------------- wide table build: local (within-chunk) tables + chunk totals; 1 wave per chunk ----------------
__global__ __launch_bounds__(256) void tabw_k(const float* __restrict__ V,
                                              int heads, int vstride,
                                              const int* __restrict__ g_sidx,
                                              const float* __restrict__ g_wN,
                                              float* __restrict__ g_A, float* __restrict__ g_S,
                                              float* __restrict__ g_TA, float* __restrict__ g_TS) {
    const int t = blockIdx.y, g = t / heads, h = t % heads;
    const int wv = threadIdx.x >> 6, lane = threadIdx.x & 63;
    const int c = blockIdx.x * 4 + wv;
    const int base = c * 16;
    const float* Vp = V + (size_t)g * NSEG * vstride + h * 64;
    const int* sidx = g_sidx + (size_t)t * NSEG + base;
    const float* wnp = g_wN + (size_t)t * NSEG + base;
    float wn[16], vv[16];
#pragma unroll
    for (int j = 0; j < 16; ++j) wn[j] = wnp[j];
#pragma unroll
    for (int j = 0; j < 16; ++j) vv[j] = Vp[(size_t)sidx[j] * vstride + lane];
    float* A = g_A + (size_t)t * TSTRIDE;
    float* S = g_S + (size_t)t * TSTRIDE;
    // exclusive within-chunk prefix (A side, leaky 0.2 weights)
    float accA = 0.f, scaA = 0.f;
#pragma unroll
    for (int j = 0; j < 16; ++j) {
        size_t pos = base + j;
        A[pos * TROW + lane] = accA;
        if (lane == 0) A[pos * TROW + 64] = scaA;
        accA += wn[j] * vv[j]; scaA += wn[j];
    }
    g_TA[((size_t)t * 128 + c) * TROW + lane] = accA;
    if (lane == 0) g_TA[((size_t)t * 128 + c) * TROW + 64] = scaA;
    // inclusive within-chunk suffix (S side, full-strength weights)
    float accS = 0.f, scaS = 0.f;
#pragma unroll
    for (int j = 15; j >= 0; --j) {
        float w = wn[j], w2 = w * w, wp = w2 * w2 * w;
        accS += wp * vv[j]; scaS += wp;
        size_t pos = base + j;
        S[pos * TROW + lane] = accS;
        if (lane == 0) S[pos * TROW + 64] = scaS;
    }
    g_TS[((size_t)t * 128 + c) * TROW + lane] = accS;
    if (lane == 0) g_TS[((size_t)t * 128 + c) * TROW + 64] = scaS;
}

// ---------------- tiny per-task scan of chunk totals: CA = excl prefix (129 rows), CS = excl suffix ----------------
__global__ __launch_bounds__(256) void scan_k(const float* __restrict__ g_TA,
                                              const float* __restrict__ g_TS,
                                              float* __restrict__ g_CA,
                                              float* __restrict__ g_CS) {
    const int t = blockIdx.x, tid = threadIdx.x;
    if (tid < 65) {
        const float* TA = g_TA + (size_t)t * 128 * TROW + tid;
        float* CA = g_CA + (size_t)t * CSTRIDE + tid;
        float run = 0.f;
#pragma unroll 4
        for (int c = 0; c < 128; ++c) { CA[c * TROW] = run; run += TA[c * TROW]; }
        CA[128 * TROW] = run;   // row 128 = full total (used by k==2048 queries)
    } else if (tid >= 128 && tid < 193) {
        const int d = tid - 128;
        const float* TS = g_TS + (size_t)t * 128 * TROW + d;
        float* CS = g_CS + (size_t)t * CSTRIDE + d;
        float run = 0.f;
#pragma unroll 4
        for (int c = 127; c >= 0; --c) { CS[c * TROW] = run; run += TS[c * TROW]; }
    }
}

// ---------------- query: binary search + 2 local rows + 2 chunk-offset rows; 16 queries per wave ----------------
template <int MODE>  // 0: ELU -> xc ; 1: ELU + log_softmax -> out
__global__ __launch_bounds__(256) void query_k(const float* __restrict__ s1_all,
                                               float* __restrict__ out,
                                               int heads, int ostride,
                                               const float* __restrict__ g_sval,
                                               const float* __restrict__ g_A,
                                               const float* __restrict__ g_S,
                                               const float* __restrict__ g_CA,
                                               const float* __restrict__ g_CS) {
    __shared__ float sval[NSEG];
    const int tid = threadIdx.x;
    const int t = blockIdx.y, g = t / heads, h = t % heads;
    const float4* sv4 = (const float4*)(g_sval + (size_t)t * NSEG);
    for (int i = tid; i < NSEG / 4; i += 256) ((float4*)sval)[i] = sv4[i];
    __syncthreads();
    const float M2 = sval[NSEG - 1];
    const int lane = tid & 63, wv = tid >> 6;
    const int q0 = blockIdx.x * 64 + wv * 16;
    const float* s1p = s1_all + (size_t)h * NTOT + (size_t)g * NSEG;
    float* outp = out + (size_t)g * NSEG * ostride + h * 64;
    const float* A = g_A + (size_t)t * TSTRIDE;
    const float* S = g_S + (size_t)t * TSTRIDE;
    const float* CA = g_CA + (size_t)t * CSTRIDE;
    const float* CS = g_CS + (size_t)t * CSTRIDE;
    int myq = q0 + (lane & 15);
    float s1v = s1p[myq];
    float th = -s1v;
    int lo = 0, hi = NSEG;
    while (lo < hi) { int mid = (lo + hi) >> 1; if (sval[mid] <= th) lo = mid + 1; else hi = mid; }
#pragma unroll 4
    for (int j = 0; j < 16; ++j) {
        int k = __shfl(lo, j, 64);
        float s1q = __shfl(s1v, j, 64);
        float accA, scaA, accS, scaS;
        if (k < NSEG) {
            const int c = k >> 4;
            const float* rowA = A + (size_t)k * TROW;
            const float* rowS = S + (size_t)k * TROW;
            const float* rowCA = CA + (size_t)c * TROW;
            const float* rowCS = CS + (size_t)c * TROW;
            accA = rowA[lane] + rowCA[lane]; scaA = rowA[64] + rowCA[64];
            accS = rowS[lane] + rowCS[lane]; scaS = rowS[64] + rowCS[64];
        } else {
            accA = CA[128 * TROW + lane]; scaA = CA[128 * TROW + 64];
            accS = 0.f; scaS = 0.f;
        }
        float cc = __expf(-0.8f * fmaxf(s1q + M2, 0.f));
        float o = (accS + cc * accA) / (scaS + cc * scaA);
        o = o > 0.f ? o : expm1f(o);  // ELU
        int q = q0 + j;
        if (MODE == 0) {
            outp[(size_t)q * ostride + lane] = o;
        } else {
            float m = o;
#pragma unroll
            for (int off = 32; off; off >>= 1) m = fmaxf(m, __shfl_xor(m, off, 64));
            float e = __expf(o - m);
#pragma unroll
            for (int off = 32; off; off >>= 1) e += __shfl_xor(e, off, 64);
            outp[(size_t)q * ostride + lane] = o - m - __logf(e);
        }
    }
}

extern "C" void kernel_launch(void* const* d_in, const int* in_sizes, int n_in,
                              void* d_out, int out_size, void* d_ws, size_t ws_size,
                              hipStream_t stream) {
    const float* h_states = (const float*)d_in[0];
    const float* W_heads = (const float*)d_in[1];
    const float* a_heads = (const float*)d_in[2];
    const float* W_out = (const float*)d_in[3];
    const float* a_out = (const float*)d_in[4];
    float* w = (float*)d_ws;
    float* hh = w + OFF_HH;
    float* xc = w + OFF_XC;
    float* hc = w + OFF_HH;  // reuse: hh dead after tabw (head layer)
    float* s1h = w + OFF_S1H;
    float* s2h = w + OFF_S2H;
    float* s1o = w + OFF_S1O;
    float* s2o = w + OFF_S2O;
    float* g_sval = w + OFF_SVAL;
    float* g_wN = w + OFF_WN;
    int* g_sidx = (int*)(w + OFF_SIDX);
    float* g_TA = w + OFF_XC;            // time-shared with xc (dead before query writes xc)
    float* g_TS = w + OFF_XC + 266240;   // "
    float* g_CA = w + OFF_CA;
    float* g_CS = w + OFF_CS;
    float* g_A = w + OFF_A;
    float* g_S = w + OFF_S;
    float* outp = (float*)d_out;

    gemm1_k<<<dim3(256, 4), 256, 0, stream>>>(h_states, W_heads, a_heads, hh, s1h, s2h);
    sort_k<<<32, 1024, 0, stream>>>(s2h, 4, g_sval, g_sidx, g_wN);
    tabw_k<<<dim3(32, 32), 256, 0, stream>>>(hh, 4, 256, g_sidx, g_wN, g_A, g_S, g_TA, g_TS);
    scan_k<<<32, 256, 0, stream>>>(g_TA, g_TS, g_CA, g_CS);
    query_k<0><<<dim3(32, 32), 256, 0, stream>>>(s1h, xc, 4, 256, g_sval, g_A, g_S, g_CA, g_CS);
    gemm2_k<<<512, 256, 0, stream>>>(xc, W_out, a_out, hc, s1o, s2o);
    sort_k<<<8, 1024, 0, stream>>>(s2o, 1, g_sval, g_sidx, g_wN);
    tabw_k<<<dim3(32, 8), 256, 0, stream>>>(hc, 1, 64, g_sidx, g_wN, g_A, g_S, g_TA, g_TS);
    scan_k<<<8, 256, 0, stream>>>(g_TA, g_TS, g_CA, g_CS);
    query_k<1><<<dim3(32, 8), 256, 0, stream>>>(s1o, outp, 1, 64, g_sval, g_A, g_S, g_CA, g_CS);
}

// Round 4
// 199.409 us; speedup vs baseline: 1.4379x; 1.0131x over previous
//
#include <hip/hip_runtime.h>
#include <math.h>

#define NTOT 16384
#define NSEG 2048

// ws float offsets
#define OFF_HH   0ull         // hh2 [4][8][2048][64] = 4194304 (hc [8][2048][64] reuses)
#define OFF_XC   4194304ull   // xc [16384][256] = 4194304 (TAS/TSA/TSS time-share)
#define OFF_S1H  8388608ull   // 65536
#define OFF_S2H  8454144ull   // 65536
#define OFF_S1O  8519680ull   // 16384
#define OFF_S2O  8536064ull   // 16384
#define OFF_SVAL 8552448ull   // 32*2048
#define OFF_WN   8617984ull   // 32*2048
#define OFF_SIDX 8683520ull   // 32*2048 ints
#define OFF_VAS  8749056ull   // 32*129*128 (scanned chunk vectors, CA|CS)
#define OFF_CSA  9277440ull   // 32*129 (scanned chunk scalar, A prefix)
#define OFF_CSS  9281568ull   // 32*129 (scanned chunk scalar, S suffix)
#define OFF_SCA  9285696ull   // 32*2048 (per-pos scalar, A)
#define OFF_SCS  9351232ull   // 32*2048 (per-pos scalar, S)
#define OFF_AS   9416768ull   // 32*2048*128 (per-pos vectors, A|S) -> end 17805376
// TAS [32][128][128] = 524288 at OFF_XC; TSA [32][128] at +524288; TSS at +528384.
// All dead before query_k<0> writes xc.

__device__ inline unsigned long long pack_key(float v, int idx) {
    unsigned u = __float_as_uint(v);
    u = (u & 0x80000000u) ? ~u : (u | 0x80000000u);
    return ((unsigned long long)u << 32) | (unsigned)idx;
}
__device__ inline float unpack_key(unsigned long long k) {
    unsigned u = (unsigned)(k >> 32);
    u = (u & 0x80000000u) ? (u ^ 0x80000000u) : ~u;
    return __uint_as_float(u);
}
__device__ inline unsigned long long shfl_xor_u64(unsigned long long x, int mask) {
    unsigned lo = (unsigned)x, hi = (unsigned)(x >> 32);
    lo = (unsigned)__shfl_xor((int)lo, mask, 64);
    hi = (unsigned)__shfl_xor((int)hi, mask, 64);
    return ((unsigned long long)hi << 32) | lo;
}

// ---------------- GEMM 1 + fused s1/s2 projection; hh written head-major [h][g][n][64] ----------------
__global__ __launch_bounds__(256) void gemm1_k(const float* __restrict__ X,
                                               const float* __restrict__ Wh,
                                               const float* __restrict__ aH,
                                               float* __restrict__ hh,
                                               float* __restrict__ s1h,
                                               float* __restrict__ s2h) {
    __shared__ float As[64][68];
    __shared__ float Bs[64][68];
    const int tid = threadIdx.x;
    const int bm = blockIdx.x, h = blockIdx.y;
    const int c0 = tid & 63, r0 = tid >> 6;
#pragma unroll
    for (int r = 0; r < 16; ++r) {
        int row = r0 + r * 4;
        As[c0][row] = X[(size_t)(bm * 64 + row) * 64 + c0];
        Bs[row][c0] = Wh[h * 4096 + row * 64 + c0];
    }
    __syncthreads();
    const int tx = tid & 15, ty = tid >> 4;
    const int m0 = ty * 4, n0 = tx * 4;
    float acc[4][4] = {};
#pragma unroll
    for (int kk = 0; kk < 64; ++kk) {
        float4 a = *(const float4*)&As[kk][m0];
        float4 b = *(const float4*)&Bs[kk][n0];
        acc[0][0] += a.x * b.x; acc[0][1] += a.x * b.y; acc[0][2] += a.x * b.z; acc[0][3] += a.x * b.w;
        acc[1][0] += a.y * b.x; acc[1][1] += a.y * b.y; acc[1][2] += a.y * b.z; acc[1][3] += a.y * b.w;
        acc[2][0] += a.z * b.x; acc[2][1] += a.z * b.y; acc[2][2] += a.z * b.z; acc[2][3] += a.z * b.w;
        acc[3][0] += a.w * b.x; acc[3][1] += a.w * b.y; acc[3][2] += a.w * b.z; acc[3][3] += a.w * b.w;
    }
    const int g = bm >> 5;                 // segment (2048 rows)
    const int nb = (bm * 64) & 2047;       // row within segment
#pragma unroll
    for (int i = 0; i < 4; ++i) {
        float4 v = make_float4(acc[i][0], acc[i][1], acc[i][2], acc[i][3]);
        *(float4*)&hh[(((size_t)h * 8 + g) * NSEG + nb + m0 + i) * 64 + n0] = v;
    }
#pragma unroll
    for (int i = 0; i < 4; ++i) {
        float p1 = 0.f, p2 = 0.f;
#pragma unroll
        for (int jj = 0; jj < 4; ++jj) {
            p1 += acc[i][jj] * aH[h * 128 + n0 + jj];
            p2 += acc[i][jj] * aH[h * 128 + 64 + n0 + jj];
        }
#pragma unroll
        for (int off = 8; off; off >>= 1) {
            p1 += __shfl_xor(p1, off, 16);
            p2 += __shfl_xor(p2, off, 16);
        }
        if (tx == 0) {
            s1h[h * NTOT + bm * 64 + m0 + i] = p1;
            s2h[h * NTOT + bm * 64 + m0 + i] = p2;
        }
    }
}

// ---------------- GEMM 2 (BM=32 tiles, 512 blocks) + fused s1/s2 projection ----------------
__global__ __launch_bounds__(256) void gemm2_k(const float* __restrict__ XC,
                                               const float* __restrict__ Wo,
                                               const float* __restrict__ aO,
                                               float* __restrict__ hc,
                                               float* __restrict__ s1o,
                                               float* __restrict__ s2o) {
    __shared__ float As[64][34];
    __shared__ float Bs[64][68];
    const int tid = threadIdx.x;
    const int bm = blockIdx.x;
    const int c0 = tid & 63, r0 = tid >> 6;
    const int tx = tid & 15, ty = tid >> 4;
    const int m0 = ty * 2, n0 = tx * 4;
    float acc[2][4] = {};
    for (int kt = 0; kt < 4; ++kt) {
#pragma unroll
        for (int r = 0; r < 8; ++r) {
            int row = r0 + r * 4;
            As[c0][row] = XC[(size_t)(bm * 32 + row) * 256 + kt * 64 + c0];
        }
#pragma unroll
        for (int r = 0; r < 16; ++r) {
            int row = r0 + r * 4;
            Bs[row][c0] = Wo[(kt * 64 + row) * 64 + c0];
        }
        __syncthreads();
#pragma unroll
        for (int kk = 0; kk < 64; ++kk) {
            float2 a = *(const float2*)&As[kk][m0];
            float4 b = *(const float4*)&Bs[kk][n0];
            acc[0][0] += a.x * b.x; acc[0][1] += a.x * b.y; acc[0][2] += a.x * b.z; acc[0][3] += a.x * b.w;
            acc[1][0] += a.y * b.x; acc[1][1] += a.y * b.y; acc[1][2] += a.y * b.z; acc[1][3] += a.y * b.w;
        }
        __syncthreads();
    }
#pragma unroll
    for (int i = 0; i < 2; ++i) {
        float4 v = make_float4(acc[i][0], acc[i][1], acc[i][2], acc[i][3]);
        *(float4*)&hc[(size_t)(bm * 32 + m0 + i) * 64 + n0] = v;
    }
#pragma unroll
    for (int i = 0; i < 2; ++i) {
        float p1 = 0.f, p2 = 0.f;
#pragma unroll
        for (int jj = 0; jj < 4; ++jj) {
            p1 += acc[i][jj] * aO[n0 + jj];
            p2 += acc[i][jj] * aO[64 + n0 + jj];
        }
#pragma unroll
        for (int off = 8; off; off >>= 1) {
            p1 += __shfl_xor(p1, off, 16);
            p2 += __shfl_xor(p2, off, 16);
        }
        if (tx == 0) {
            s1o[bm * 32 + m0 + i] = p1;
            s2o[bm * 32 + m0 + i] = p2;
        }
    }
}

// ---------------- lean bitonic sort: 1 block per task, double-buffered LDS exchanges ----------------
__global__ __launch_bounds__(1024) void sort_k(const float* __restrict__ s2_all,
                                               int heads,
                                               float* __restrict__ g_sval,
                                               int* __restrict__ g_sidx,
                                               float* __restrict__ g_wN) {
    __shared__ unsigned long long sA[2][1024];
    __shared__ unsigned long long sB[2][1024];
    __shared__ float sM2;
    const int tid = threadIdx.x, t = blockIdx.x;
    const int g = t / heads, h = t % heads;
    const float* s2p = s2_all + (size_t)h * NTOT + (size_t)g * NSEG;

    unsigned long long a0 = pack_key(s2p[tid], tid);
    unsigned long long a1 = pack_key(s2p[tid + 1024], tid + 1024);
    int p = 0;
    for (int k = 2; k <= 2048; k <<= 1) {
        const bool up0 = (tid & k) == 0;
        const bool up1 = (((tid + 1024) & k) == 0);
        for (int j = k >> 1; j > 0; j >>= 1) {
            if (j >= 1024) {
                unsigned long long lo = a0 < a1 ? a0 : a1;
                unsigned long long hi = a0 < a1 ? a1 : a0;
                a0 = up0 ? lo : hi;
                a1 = up0 ? hi : lo;
            } else if (j >= 64) {
                sA[p][tid] = a0; sB[p][tid] = a1;
                __syncthreads();
                unsigned long long q0 = sA[p][tid ^ j], q1 = sB[p][tid ^ j];
                bool lower = (tid & j) == 0;
                a0 = ((a0 < q0) == (lower == up0)) ? a0 : q0;
                a1 = ((a1 < q1) == (lower == up1)) ? a1 : q1;
                p ^= 1;
            } else {
                unsigned long long q0 = shfl_xor_u64(a0, j);
                unsigned long long q1 = shfl_xor_u64(a1, j);
                bool lower = (tid & j) == 0;
                a0 = ((a0 < q0) == (lower == up0)) ? a0 : q0;
                a1 = ((a1 < q1) == (lower == up1)) ? a1 : q1;
            }
        }
    }
    float v0 = unpack_key(a0), v1 = unpack_key(a1);
    if (tid == 1023) sM2 = v1;
    __syncthreads();
    const float M2 = sM2;
    int i0 = (int)(unsigned)(a0 & 0xffffffffu);
    int i1 = (int)(unsigned)(a1 & 0xffffffffu);
    float w0 = __expf(0.2f * (v0 - M2));
    float w1 = __expf(0.2f * (v1 - M2));
    size_t o = (size_t)t * NSEG;
    g_sval[o + tid] = v0; g_sval[o + tid + 1024] = v1;
    g_sidx[o + tid] = i0; g_sidx[o + tid + 1024] = i1;
    g_wN[o + tid] = w0;   g_wN[o + tid + 1024] = w1;
}

// ---------------- wide table build: aligned AS rows + scalar arrays; XCD-clustered tasks ----------------
__global__ __launch_bounds__(256) void tabw_k(const float* __restrict__ V,
                                              int heads, int ntask,
                                              const int* __restrict__ g_sidx,
                                              const float* __restrict__ g_wN,
                                              float* __restrict__ AS,
                                              float* __restrict__ SCA, float* __restrict__ SCS,
                                              float* __restrict__ TAS,
                                              float* __restrict__ TSA, float* __restrict__ TSS) {
    const int L = blockIdx.x + (int)(gridDim.x * blockIdx.y);
    const int xcd = L & 7, slot = L >> 3;
    const int tpx = ntask >> 3;                    // tasks per XCD
    const int t = xcd * tpx + (slot >> 5);
    const int u = slot & 31;
    const int wv = threadIdx.x >> 6, lane = threadIdx.x & 63;
    const int c = u * 4 + wv, base = c * 16;
    const int g = t / heads, h = t % heads;
    const int seg = h * (ntask / heads) + g;       // V segment [seg][2048][64]
    const float* Vp = V + (size_t)seg * NSEG * 64;
    const int* sidx = g_sidx + (size_t)t * NSEG + base;
    const float* wnp = g_wN + (size_t)t * NSEG + base;
    float wn[16], vv[16];
#pragma unroll
    for (int j = 0; j < 16; ++j) wn[j] = wnp[j];
#pragma unroll
    for (int j = 0; j < 16; ++j) vv[j] = Vp[(size_t)sidx[j] * 64 + lane];
    float* ASp = AS + (size_t)t * NSEG * 128;
    // exclusive within-chunk prefix (A half of row)
    float accA = 0.f, scaA = 0.f;
#pragma unroll
    for (int j = 0; j < 16; ++j) {
        size_t pos = base + j;
        ASp[pos * 128 + lane] = accA;
        if (lane == 0) SCA[(size_t)t * NSEG + pos] = scaA;
        accA += wn[j] * vv[j]; scaA += wn[j];
    }
    TAS[((size_t)t * 128 + c) * 128 + lane] = accA;
    if (lane == 0) TSA[t * 128 + c] = scaA;
    // inclusive within-chunk suffix (S half of row)
    float accS = 0.f, scaS = 0.f;
#pragma unroll
    for (int j = 15; j >= 0; --j) {
        float w = wn[j], w2 = w * w, wp = w2 * w2 * w;
        accS += wp * vv[j]; scaS += wp;
        size_t pos = base + j;
        ASp[pos * 128 + 64 + lane] = accS;
        if (lane == 0) SCS[(size_t)t * NSEG + pos] = scaS;
    }
    TAS[((size_t)t * 128 + c) * 128 + 64 + lane] = accS;
    if (lane == 0) TSS[t * 128 + c] = scaS;
}

// ---------------- tiny per-task scan of chunk totals ----------------
__global__ __launch_bounds__(256) void scan_k(const float* __restrict__ TAS,
                                              const float* __restrict__ TSA,
                                              const float* __restrict__ TSS,
                                              float* __restrict__ VAS,
                                              float* __restrict__ CSA, float* __restrict__ CSS) {
    const int t = blockIdx.x, tid = threadIdx.x;
    const float* T = TAS + (size_t)t * 128 * 128;
    float* Vo = VAS + (size_t)t * 129 * 128;
    if (tid < 64) {                 // A-vector: exclusive prefix over chunks
        float run = 0.f;
#pragma unroll 4
        for (int c = 0; c < 128; ++c) { Vo[c * 128 + tid] = run; run += T[c * 128 + tid]; }
        Vo[128 * 128 + tid] = run;  // full total (k==2048 queries)
    } else if (tid < 128) {         // S-vector: exclusive suffix over chunks
        float run = 0.f;
#pragma unroll 4
        for (int c = 127; c >= 0; --c) { Vo[c * 128 + tid] = run; run += T[c * 128 + tid]; }
    } else if (tid == 128) {        // A-scalar
        float run = 0.f;
        for (int c = 0; c < 128; ++c) { CSA[t * 129 + c] = run; run += TSA[t * 128 + c]; }
        CSA[t * 129 + 128] = run;
    } else if (tid == 129) {        // S-scalar
        float run = 0.f;
        for (int c = 127; c >= 0; --c) { CSS[t * 129 + c] = run; run += TSS[t * 128 + c]; }
    }
}

// ---------------- query: binary search + 1 aligned 512B row + chunk row; XCD-clustered ----------------
template <int MODE>  // 0: ELU -> xc ; 1: ELU + log_softmax -> out
__global__ __launch_bounds__(256) void query_k(const float* __restrict__ s1_all,
                                               float* __restrict__ out,
                                               int heads, int ntask, int ostride,
                                               const float* __restrict__ g_sval,
                                               const float* __restrict__ AS,
                                               const float* __restrict__ SCA, const float* __restrict__ SCS,
                                               const float* __restrict__ VAS,
                                               const float* __restrict__ CSA, const float* __restrict__ CSS) {
    __shared__ float sval[NSEG];
    const int tid = threadIdx.x;
    const int L = blockIdx.x + (int)(gridDim.x * blockIdx.y);
    const int xcd = L & 7, slot = L >> 3;
    const int tpx = ntask >> 3;
    const int t = xcd * tpx + (slot >> 5);
    const int u = slot & 31;
    const int g = t / heads, h = t % heads;
    const float4* sv4 = (const float4*)(g_sval + (size_t)t * NSEG);
    for (int i = tid; i < NSEG / 4; i += 256) ((float4*)sval)[i] = sv4[i];
    __syncthreads();
    const float M2 = sval[NSEG - 1];
    const int lane = tid & 63, wv = tid >> 6;
    const int q0 = u * 64 + wv * 16;
    const float* s1p = s1_all + (size_t)h * NTOT + (size_t)g * NSEG;
    float* outp = out + (size_t)g * NSEG * ostride + h * 64;
    const float* ASp = AS + (size_t)t * NSEG * 128;
    const float* VASp = VAS + (size_t)t * 129 * 128;
    const float* scA = SCA + (size_t)t * NSEG;
    const float* scS = SCS + (size_t)t * NSEG;
    const float* csA = CSA + (size_t)t * 129;
    const float* csS = CSS + (size_t)t * 129;
    int myq = q0 + (lane & 15);
    float s1v = s1p[myq];
    float th = -s1v;
    int lo = 0, hi = NSEG;
    while (lo < hi) { int mid = (lo + hi) >> 1; if (sval[mid] <= th) lo = mid + 1; else hi = mid; }
#pragma unroll 4
    for (int j = 0; j < 16; ++j) {
        int k = __shfl(lo, j, 64);
        float s1q = __shfl(s1v, j, 64);
        float accA, scaA, accS, scaS;
        if (k < NSEG) {
            const int c = k >> 4;
            const float* rowP = ASp + (size_t)k * 128;
            const float* rowC = VASp + (size_t)c * 128;
            accA = rowP[lane] + rowC[lane];
            accS = rowP[64 + lane] + rowC[64 + lane];
            scaA = scA[k] + csA[c];
            scaS = scS[k] + csS[c];
        } else {
            accA = VASp[128 * 128 + lane]; scaA = csA[128];
            accS = 0.f; scaS = 0.f;
        }
        float cc = __expf(-0.8f * fmaxf(s1q + M2, 0.f));
        float o = (accS + cc * accA) / (scaS + cc * scaA);
        o = o > 0.f ? o : expm1f(o);  // ELU
        int q = q0 + j;
        if (MODE == 0) {
            outp[(size_t)q * ostride + lane] = o;
        } else {
            float m = o;
#pragma unroll
            for (int off = 32; off; off >>= 1) m = fmaxf(m, __shfl_xor(m, off, 64));
            float e = __expf(o - m);
#pragma unroll
            for (int off = 32; off; off >>= 1) e += __shfl_xor(e, off, 64);
            outp[(size_t)q * ostride + lane] = o - m - __logf(e);
        }
    }
}

extern "C" void kernel_launch(void* const* d_in, const int* in_sizes, int n_in,
                              void* d_out, int out_size, void* d_ws, size_t ws_size,
                              hipStream_t stream) {
    const float* h_states = (const float*)d_in[0];
    const float* W_heads = (const float*)d_in[1];
    const float* a_heads = (const float*)d_in[2];
    const float* W_out = (const float*)d_in[3];
    const float* a_out = (const float*)d_in[4];
    float* w = (float*)d_ws;
    float* hh = w + OFF_HH;
    float* xc = w + OFF_XC;
    float* hc = w + OFF_HH;              // reuse: hh dead after tabw (head layer)
    float* s1h = w + OFF_S1H;
    float* s2h = w + OFF_S2H;
    float* s1o = w + OFF_S1O;
    float* s2o = w + OFF_S2O;
    float* g_sval = w + OFF_SVAL;
    float* g_wN = w + OFF_WN;
    int* g_sidx = (int*)(w + OFF_SIDX);
    float* TAS = w + OFF_XC;             // time-shared with xc
    float* TSA = w + OFF_XC + 524288;
    float* TSS = w + OFF_XC + 528384;
    float* VAS = w + OFF_VAS;
    float* CSA = w + OFF_CSA;
    float* CSS = w + OFF_CSS;
    float* SCA = w + OFF_SCA;
    float* SCS = w + OFF_SCS;
    float* AS = w + OFF_AS;
    float* outp = (float*)d_out;

    gemm1_k<<<dim3(256, 4), 256, 0, stream>>>(h_states, W_heads, a_heads, hh, s1h, s2h);
    sort_k<<<32, 1024, 0, stream>>>(s2h, 4, g_sval, g_sidx, g_wN);
    tabw_k<<<dim3(32, 32), 256, 0, stream>>>(hh, 4, 32, g_sidx, g_wN, AS, SCA, SCS, TAS, TSA, TSS);
    scan_k<<<32, 256, 0, stream>>>(TAS, TSA, TSS, VAS, CSA, CSS);
    query_k<0><<<dim3(32, 32), 256, 0, stream>>>(s1h, xc, 4, 32, 256, g_sval, AS, SCA, SCS, VAS, CSA, CSS);
    gemm2_k<<<512, 256, 0, stream>>>(xc, W_out, a_out, hc, s1o, s2o);
    sort_k<<<8, 1024, 0, stream>>>(s2o, 1, g_sval, g_sidx, g_wN);
    tabw_k<<<dim3(32, 8), 256, 0, stream>>>(hc, 1, 8, g_sidx, g_wN, AS, SCA, SCS, TAS, TSA, TSS);
    scan_k<<<8, 256, 0, stream>>>(TAS, TSA, TSS, VAS, CSA, CSS);
    query_k<1><<<dim3(32, 8), 256, 0, stream>>>(s1o, outp, 1, 8, 64, g_sval, AS, SCA, SCS, VAS, CSA, CSS);
}